// Round 10
// baseline (799.169 us; speedup 1.0000x reference)
//
#include <hip/hip_runtime.h>
#include <math.h>

namespace {

constexpr int SEQ  = 16;
constexpr int CDIM = 256;
constexpr int NLAT = 8;
constexpr int NR   = 48;   // 3*SEQ state rows (l,a,v)

// Pack-butterfly reduce: acc[8] summed over the 32-lane group.
// Returns, on lane l, the group-wide sum of acc[l&7] (duplicated 4x).
__device__ __forceinline__ float reduce32x8(const float acc[8], int ln) {
    float p4[4];
    #pragma unroll
    for (int i = 0; i < 4; ++i) {
        const float a  = acc[2*i]   + __shfl_xor(acc[2*i],   1);
        const float bq = acc[2*i+1] + __shfl_xor(acc[2*i+1], 1);
        p4[i] = (ln & 1) ? bq : a;
    }
    float p2[2];
    #pragma unroll
    for (int i = 0; i < 2; ++i) {
        const float a  = p4[2*i]   + __shfl_xor(p4[2*i],   2);
        const float bq = p4[2*i+1] + __shfl_xor(p4[2*i+1], 2);
        p2[i] = (ln & 2) ? bq : a;
    }
    const float a  = p2[0] + __shfl_xor(p2[0], 4);
    const float bq = p2[1] + __shfl_xor(p2[1], 4);
    float r = (ln & 4) ? bq : a;
    r += __shfl_xor(r, 8);
    r += __shfl_xor(r, 16);
    return r;
}

// One block (512 threads, 8 waves) per batch. 67KB LDS -> 2 blocks/CU -> 16 waves/CU.
__global__ __launch_bounds__(512, 4)
void bottleneck_fusion_kernel(const float* __restrict__ l1,
                              const float* __restrict__ a1,
                              const float* __restrict__ v1,
                              const float* __restrict__ lat,
                              const float* __restrict__ psl,
                              const float* __restrict__ psa,
                              const float* __restrict__ psv,
                              float* __restrict__ out)
{
    __shared__ __align__(16) float st[NR * CDIM];     // 48x256 state (l,a,v)
    __shared__ __align__(16) float fz[NLAT * CDIM];   // fused rows
    __shared__ __align__(16) float latl[NLAT * CDIM]; // latents pre-scaled by C^-0.5
    __shared__ __align__(16) float s1t[NR * NLAT];    // scores1/weights1 [k][q]

    const int t   = threadIdx.x;
    const int wv  = t >> 6;   // wave 0..7
    const int ln  = t & 63;   // lane in wave
    const int g   = t >> 5;   // 32-lane group 0..15 (owns rows 3g..3g+2)
    const int l32 = t & 31;
    const int b   = blockIdx.x;

    // ---- stage state (6 float4/thread, coalesced) + pre-scaled latents
    for (int idx = t; idx < NR * 64; idx += 512) {
        const int r = idx >> 6, c4 = (idx & 63) * 4;
        const float* src = (r < 16) ? l1 : (r < 32) ? a1 : v1;
        *(float4*)&st[r * CDIM + c4] =
            *(const float4*)(src + ((size_t)b * SEQ + (r & 15)) * CDIM + c4);
    }
    {
        const int q = t >> 6, c4 = (t & 63) * 4;  // exactly 512 float4s
        float4 lv = *(const float4*)(lat + q * CDIM + c4);
        lv.x *= 0.0625f; lv.y *= 0.0625f; lv.z *= 0.0625f; lv.w *= 0.0625f;
        *(float4*)&latl[q * CDIM + c4] = lv;
    }
    const float sc_l = psl[0], sc_a = psa[0], sc_v = psv[0];
    __syncthreads();

    for (int it = 0; it < 3; ++it) {
        // ===== P1a: s1t[k][q] = latl[q] . st[k]  (group owns 3 rows, 32B cols/lane)
        {
            float lf[NLAT][8];
            #pragma unroll
            for (int q = 0; q < NLAT; ++q) {
                *(float4*)&lf[q][0] = *(const float4*)&latl[q * CDIM + l32 * 8];
                *(float4*)&lf[q][4] = *(const float4*)&latl[q * CDIM + l32 * 8 + 4];
            }
            #pragma unroll
            for (int rr = 0; rr < 3; ++rr) {
                const int r = g * 3 + rr;
                float x[8];
                *(float4*)&x[0] = *(const float4*)&st[r * CDIM + l32 * 8];
                *(float4*)&x[4] = *(const float4*)&st[r * CDIM + l32 * 8 + 4];
                float acc[NLAT];
                #pragma unroll
                for (int q = 0; q < NLAT; ++q) {
                    float s = 0.f;
                    #pragma unroll
                    for (int c = 0; c < 8; ++c) s = fmaf(x[c], lf[q][c], s);
                    acc[q] = s;
                }
                const float s = reduce32x8(acc, l32);
                if (l32 < NLAT) s1t[r * NLAT + l32] = s;
            }
        }
        __syncthreads();

        // ===== softmax over 48 keys; wave wv owns latent q=wv, lane=key
        {
            const int q = wv, k = ln;
            const bool act = (k < NR);
            const float v = act ? s1t[k * NLAT + q] : -3.4e38f;
            float m = v;
            #pragma unroll
            for (int d = 1; d <= 32; d <<= 1) m = fmaxf(m, __shfl_xor(m, d));
            const float e = act ? __expf(v - m) : 0.f;
            float ssum = e;
            #pragma unroll
            for (int d = 1; d <= 32; d <<= 1) ssum += __shfl_xor(ssum, d);
            if (act) s1t[k * NLAT + q] = e / ssum;
        }
        __syncthreads();

        // ===== P1c: fz[q][c] = sum_k w1[k][q] * st[k][c]
        // thread owns column c and a q-nibble; weight reads are wave-broadcast b128
        {
            const int c = t & 255, nib = t >> 8;
            float f0 = 0.f, f1 = 0.f, f2 = 0.f, f3 = 0.f;
            #pragma unroll 4
            for (int k = 0; k < NR; ++k) {
                const float4 w4 = *(const float4*)&s1t[k * NLAT + nib * 4];
                const float xv = st[k * CDIM + c];
                f0 = fmaf(w4.x, xv, f0);
                f1 = fmaf(w4.y, xv, f1);
                f2 = fmaf(w4.z, xv, f2);
                f3 = fmaf(w4.w, xv, f3);
            }
            fz[(nib * 4 + 0) * CDIM + c] = f0;
            fz[(nib * 4 + 1) * CDIM + c] = f1;
            fz[(nib * 4 + 2) * CDIM + c] = f2;
            fz[(nib * 4 + 3) * CDIM + c] = f3;
        }
        __syncthreads();

        // ===== P2 fused: scores2 -> softmax(8) -> row update, group-local
        // (rows disjoint per group => no inner barrier, no s2 buffer)
        // it==2: only row 15 feeds the output -> group 5 (rows 15..17) only.
        if (it < 2 || g == 5) {
            float ff[NLAT][8];
            #pragma unroll
            for (int j = 0; j < NLAT; ++j) {
                *(float4*)&ff[j][0] = *(const float4*)&fz[j * CDIM + l32 * 8];
                *(float4*)&ff[j][4] = *(const float4*)&fz[j * CDIM + l32 * 8 + 4];
            }
            #pragma unroll
            for (int rr = 0; rr < 3; ++rr) {
                const int r = g * 3 + rr;
                float x[8];
                *(float4*)&x[0] = *(const float4*)&st[r * CDIM + l32 * 8];
                *(float4*)&x[4] = *(const float4*)&st[r * CDIM + l32 * 8 + 4];
                float acc[NLAT];
                #pragma unroll
                for (int j = 0; j < NLAT; ++j) {
                    float s = 0.f;
                    #pragma unroll
                    for (int c = 0; c < 8; ++c) s = fmaf(x[c], ff[j][c], s);
                    acc[j] = s;
                }
                const float s = reduce32x8(acc, l32) * 0.0625f;
                // softmax across the 8-lane octet (this lane's score is j = ln&7)
                float m = s;
                m = fmaxf(m, __shfl_xor(m, 1));
                m = fmaxf(m, __shfl_xor(m, 2));
                m = fmaxf(m, __shfl_xor(m, 4));
                const float e = __expf(s - m);
                float ssum = e;
                ssum += __shfl_xor(ssum, 1);
                ssum += __shfl_xor(ssum, 2);
                ssum += __shfl_xor(ssum, 4);
                const float wq = e / ssum;
                // PV: fetch each octet weight on the fly (no w[8] array -> lower VGPR peak)
                float o[8] = {0,0,0,0,0,0,0,0};
                const int obase = ln & ~7;
                #pragma unroll
                for (int j = 0; j < NLAT; ++j) {
                    const float wj = __shfl(wq, obase | j);
                    #pragma unroll
                    for (int c = 0; c < 8; ++c) o[c] = fmaf(wj, ff[j][c], o[c]);
                }
                const float sc = (r < 16) ? sc_l : (r < 32) ? sc_a : sc_v;
                #pragma unroll
                for (int c = 0; c < 8; ++c) x[c] = fmaf(sc, o[c], x[c]);
                *(float4*)&st[r * CDIM + l32 * 8]     = *(float4*)&x[0];
                *(float4*)&st[r * CDIM + l32 * 8 + 4] = *(float4*)&x[4];
            }
        }
        __syncthreads();
    }

    // output = l1 row 15 (last time step)
    if (t < 64) {
        *(float4*)(out + (size_t)b * CDIM + t * 4) =
            *(const float4*)&st[15 * CDIM + t * 4];
    }
}

} // namespace

extern "C" void kernel_launch(void* const* d_in, const int* in_sizes, int n_in,
                              void* d_out, int out_size, void* d_ws, size_t ws_size,
                              hipStream_t stream) {
    const float* l1  = (const float*)d_in[0];
    const float* a1  = (const float*)d_in[1];
    const float* v1  = (const float*)d_in[2];
    const float* lat = (const float*)d_in[3];
    const float* psl = (const float*)d_in[4];
    const float* psa = (const float*)d_in[5];
    const float* psv = (const float*)d_in[6];
    float* out = (float*)d_out;

    const int B = in_sizes[0] / (SEQ * CDIM);  // 8192
    dim3 grid(B), block(512);
    hipLaunchKernelGGL(bottleneck_fusion_kernel, grid, block, 0, stream,
                       l1, a1, v1, lat, psl, psa, psv, out);
}